// Round 2
// baseline (681.512 us; speedup 1.0000x reference)
//
#include <hip/hip_runtime.h>

typedef float floatx4 __attribute__((ext_vector_type(4)));
typedef short short8 __attribute__((ext_vector_type(8)));

#define HIDDEN 2048
#define NH 16
#define NKV 4
#define HD 128
#define NB 2
#define SEQ 2048
#define MT (NB * SEQ)  // 4096

__device__ __forceinline__ unsigned short f2bf(float x) {
  union { float f; unsigned u; } v; v.f = x;
  unsigned r = v.u + 0x7FFFu + ((v.u >> 16) & 1u);  // RNE
  return (unsigned short)(r >> 16);
}

// ---------------- contiguous fp32 -> bf16 cast ----------------
__global__ void cast_bf16_kernel(const float* __restrict__ in,
                                 unsigned short* __restrict__ out, int n4) {
  int i = blockIdx.x * 256 + threadIdx.x;
  if (i >= n4) return;
  float4 v = ((const float4*)in)[i];
  ushort4 o;
  o.x = f2bf(v.x); o.y = f2bf(v.y); o.z = f2bf(v.z); o.w = f2bf(v.w);
  ((ushort4*)out)[i] = o;
}

// ------- transpose + cast: W[Kd][Nd] fp32 -> Wt[Nd][Kd] bf16 -------
__global__ void transpose_bf16_kernel(const float* __restrict__ W,
                                      unsigned short* __restrict__ Wt,
                                      int Kd, int Nd) {
  __shared__ float tile[32][33];
  int n0 = blockIdx.x * 32, k0 = blockIdx.y * 32;
  int tx = threadIdx.x, ty = threadIdx.y;
  for (int i = 0; i < 32; i += 8)
    tile[ty + i][tx] = W[(size_t)(k0 + ty + i) * Nd + n0 + tx];
  __syncthreads();
  for (int i = 0; i < 32; i += 8)
    Wt[(size_t)(n0 + ty + i) * Kd + k0 + tx] = f2bf(tile[tx][ty + i]);
}

// ------- C[M][N] fp32 = A[M][K] bf16 @ Bt[N][K]^T bf16 -------
// 128x128 tile, BK=32, 4 waves in 2x2, 16x16x32 MFMA.
#define LDK 40  // padded LDS k-stride (bf16 units): 80B rows -> 2-way bank alias (free)

__global__ __launch_bounds__(256, 2)
void gemm_bf16_kernel(const unsigned short* __restrict__ A,
                      const unsigned short* __restrict__ Bt,
                      float* __restrict__ C, int M, int N, int K) {
  __shared__ unsigned short As[128 * LDK];
  __shared__ unsigned short Bs[128 * LDK];
  const int tid = threadIdx.x;
  const int wave = tid >> 6, lane = tid & 63;
  const int quad = lane >> 4, l16 = lane & 15;
  const int m0 = blockIdx.x * 128, n0 = blockIdx.y * 128;
  const int wm = (wave >> 1) * 64, wn = (wave & 1) * 64;

  floatx4 acc[4][4] = {};

  for (int kt = 0; kt < K; kt += 32) {
    __syncthreads();
    for (int c = tid; c < 512; c += 256) {
      int r = c >> 2, c4 = c & 3;
      uint4 w = *(const uint4*)&A[(size_t)(m0 + r) * K + kt + c4 * 8];
      *(uint2*)&As[r * LDK + c4 * 8] = make_uint2(w.x, w.y);
      *(uint2*)&As[r * LDK + c4 * 8 + 4] = make_uint2(w.z, w.w);
      uint4 v = *(const uint4*)&Bt[(size_t)(n0 + r) * K + kt + c4 * 8];
      *(uint2*)&Bs[r * LDK + c4 * 8] = make_uint2(v.x, v.y);
      *(uint2*)&Bs[r * LDK + c4 * 8 + 4] = make_uint2(v.z, v.w);
    }
    __syncthreads();
    short8 af[4], bf[4];
#pragma unroll
    for (int i = 0; i < 4; i++)
      af[i] = *(const short8*)&As[(wm + i * 16 + l16) * LDK + quad * 8];
#pragma unroll
    for (int j = 0; j < 4; j++)
      bf[j] = *(const short8*)&Bs[(wn + j * 16 + l16) * LDK + quad * 8];
#pragma unroll
    for (int i = 0; i < 4; i++)
#pragma unroll
      for (int j = 0; j < 4; j++)
        acc[i][j] = __builtin_amdgcn_mfma_f32_16x16x32_bf16(af[i], bf[j], acc[i][j], 0, 0, 0);
  }
#pragma unroll
  for (int i = 0; i < 4; i++) {
    int row = m0 + wm + i * 16 + quad * 4;
#pragma unroll
    for (int j = 0; j < 4; j++) {
      int col = n0 + wn + j * 16 + l16;
#pragma unroll
      for (int r = 0; r < 4; r++)
        C[(size_t)(row + r) * N + col] = acc[i][j][r];
    }
  }
}

// ------- per-head RMSNorm + RoPE + cast, X[MT][Nh*HD] fp32 -> out[NB][Nh][SEQ][HD] bf16 -------
__global__ void norm_rope_kernel(const float* __restrict__ X,
                                 const float* __restrict__ w,
                                 const float* __restrict__ cosb,
                                 const float* __restrict__ sinb,
                                 unsigned short* __restrict__ out, int Nh) {
  int rid = blockIdx.x * 4 + (threadIdx.x >> 6);
  int lane = threadIdx.x & 63;
  int m = rid / Nh, h = rid - m * Nh;
  int b = m / SEQ, s = m - b * SEQ;
  const float* x = X + (size_t)m * (Nh * HD) + h * HD;
  float x0 = x[lane], x1 = x[lane + 64];
  float ssq = x0 * x0 + x1 * x1;
#pragma unroll
  for (int off = 32; off >= 1; off >>= 1) ssq += __shfl_xor(ssq, off, 64);
  float rr = rsqrtf(ssq * (1.0f / 128.0f) + 1e-6f);
  float xn0 = x0 * rr * w[lane];
  float xn1 = x1 * rr * w[lane + 64];
  float c0 = cosb[s * HD + lane], c1 = cosb[s * HD + lane + 64];
  float s0 = sinb[s * HD + lane], s1 = sinb[s * HD + lane + 64];
  unsigned short* op = out + (size_t)((b * Nh + h) * SEQ + s) * HD;
  op[lane] = f2bf(xn0 * c0 - xn1 * s0);       // d < 64:  x*c - x[d+64]*s
  op[lane + 64] = f2bf(xn1 * c1 + xn0 * s1);  // d >= 64: x*c + x[d-64]*s
}

// ------- V cast + transpose: Vraw[MT][NKV*HD] fp32 -> Vt[NB][NKV][HD][SEQ] bf16 -------
__global__ void v_cast_kernel(const float* __restrict__ Vraw,
                              unsigned short* __restrict__ Vt) {
  int idx = blockIdx.x * 256 + threadIdx.x;  // NB*NKV*HD*SEQ total
  int s = idx & (SEQ - 1);
  int t = idx >> 11;
  int d = t & (HD - 1);
  t >>= 7;
  int kv = t & (NKV - 1);
  int b = t >> 2;
  float v = Vraw[(size_t)(b * SEQ + s) * (NKV * HD) + kv * HD + d];
  Vt[idx] = f2bf(v);
}

// ------- flash attention, GQA, causal -------
// block = 4 waves; 64 q-rows per block; kv tiles of 64; each wave owns 16 q-rows x all kv.
#define LQ 136  // LDS stride for [*][128] bf16 tiles (272B rows, 16B-aligned, 2-way alias)
#define LV 72   // LDS stride for [*][64]  bf16 tiles (144B rows, 16B-aligned, 2-way alias)

__global__ __launch_bounds__(256, 2)
void attn_kernel(const unsigned short* __restrict__ Q,   // [NB][NH][SEQ][HD]
                 const unsigned short* __restrict__ Kb,  // [NB][NKV][SEQ][HD]
                 const unsigned short* __restrict__ Vt,  // [NB][NKV][HD][SEQ]
                 unsigned short* __restrict__ O) {       // [MT][NH*HD]
  __shared__ unsigned short Qs[64 * LQ];
  __shared__ unsigned short KVs[128 * LV];  // union: K-tile [64][LQ] (8696 used) / V-tile [128][LV]
  __shared__ unsigned short Ps[64 * LV];
  const int tid = threadIdx.x;
  const int wave = tid >> 6, lane = tid & 63;
  const int quad = lane >> 4, l16 = lane & 15;
  const int qt = blockIdx.x, bh = blockIdx.y;
  const int b = bh >> 4, h = bh & 15, kvh = h >> 2;
  const int q0 = qt * 64;

  // stage Q tile: 64 rows x 128 bf16 = 1024 x 16B
  const unsigned short* Qg = Q + (size_t)((b * NH + h) * SEQ + q0) * HD;
  for (int c = tid; c < 1024; c += 256) {
    int r = c >> 4, c8 = c & 15;
    *(uint4*)&Qs[r * LQ + c8 * 8] = *(const uint4*)&Qg[r * HD + c8 * 8];
  }

  floatx4 oacc[8] = {};
  float mrow[4] = {-1e30f, -1e30f, -1e30f, -1e30f};
  float lrow[4] = {0.f, 0.f, 0.f, 0.f};
  const float scale = 0.08838834764831845f;  // 1/sqrt(128)
  const unsigned short* Kg0 = Kb + (size_t)((b * NKV + kvh) * SEQ) * HD;
  const unsigned short* Vg0 = Vt + (size_t)((b * NKV + kvh) * HD) * SEQ;

  for (int kt = 0; kt <= qt; ++kt) {
    __syncthreads();  // prev PV done with KVs/Ps (and Q staged, first iter)
    // stage K tile: 64 rows x 128 bf16 = 1024 x 16B
    for (int c = tid; c < 1024; c += 256) {
      int r = c >> 4, c8 = c & 15;
      *(uint4*)&KVs[r * LQ + c8 * 8] = *(const uint4*)&Kg0[(size_t)(kt * 64 + r) * HD + c8 * 8];
    }
    __syncthreads();
    // S = Q @ K^T  (wave rows: wave*16.., cols: all 64)
    floatx4 sc[4] = {};
#pragma unroll
    for (int ks = 0; ks < 4; ++ks) {
      short8 af = *(const short8*)&Qs[(wave * 16 + l16) * LQ + ks * 32 + quad * 8];
#pragma unroll
      for (int j = 0; j < 4; ++j) {
        short8 bf = *(const short8*)&KVs[(j * 16 + l16) * LQ + ks * 32 + quad * 8];
        sc[j] = __builtin_amdgcn_mfma_f32_16x16x32_bf16(af, bf, sc[j], 0, 0, 0);
      }
    }
#pragma unroll
    for (int j = 0; j < 4; ++j)
#pragma unroll
      for (int r = 0; r < 4; ++r) sc[j][r] *= scale;
    if (kt == qt) {  // diagonal tile: causal mask
      int rowg = q0 + wave * 16 + quad * 4;
#pragma unroll
      for (int j = 0; j < 4; ++j) {
        int col = q0 + j * 16 + l16;
#pragma unroll
        for (int r = 0; r < 4; ++r)
          if (col > rowg + r) sc[j][r] = -1e30f;
      }
    }
    // online softmax; row r lives in this 16-lane group (same quad)
    float alpha[4];
#pragma unroll
    for (int r = 0; r < 4; ++r) {
      float mx = fmaxf(fmaxf(sc[0][r], sc[1][r]), fmaxf(sc[2][r], sc[3][r]));
#pragma unroll
      for (int off = 1; off < 16; off <<= 1) mx = fmaxf(mx, __shfl_xor(mx, off, 64));
      float mn = fmaxf(mrow[r], mx);
      alpha[r] = __expf(mrow[r] - mn);
      mrow[r] = mn;
      float rs = 0.f;
#pragma unroll
      for (int j = 0; j < 4; ++j) {
        float p = __expf(sc[j][r] - mn);
        sc[j][r] = p;
        rs += p;
      }
#pragma unroll
      for (int off = 1; off < 16; off <<= 1) rs += __shfl_xor(rs, off, 64);
      lrow[r] = lrow[r] * alpha[r] + rs;
    }
#pragma unroll
    for (int t = 0; t < 8; ++t)
#pragma unroll
      for (int r = 0; r < 4; ++r) oacc[t][r] *= alpha[r];
    // P (C-layout) -> LDS -> A-layout for PV
#pragma unroll
    for (int j = 0; j < 4; ++j)
#pragma unroll
      for (int r = 0; r < 4; ++r)
        Ps[(wave * 16 + quad * 4 + r) * LV + j * 16 + l16] = f2bf(sc[j][r]);
    __syncthreads();  // all waves' K reads done; Ps visible
    // stage V tile as [d=128][kv=64] = 1024 x 16B
    for (int c = tid; c < 1024; c += 256) {
      int d = c >> 3, c8 = c & 7;
      *(uint4*)&KVs[d * LV + c8 * 8] = *(const uint4*)&Vg0[(size_t)d * SEQ + kt * 64 + c8 * 8];
    }
    __syncthreads();
    // O += P @ V
#pragma unroll
    for (int ks = 0; ks < 2; ++ks) {
      short8 af = *(const short8*)&Ps[(wave * 16 + l16) * LV + ks * 32 + quad * 8];
#pragma unroll
      for (int t = 0; t < 8; ++t) {
        short8 bf = *(const short8*)&KVs[(t * 16 + l16) * LV + ks * 32 + quad * 8];
        oacc[t] = __builtin_amdgcn_mfma_f32_16x16x32_bf16(af, bf, oacc[t], 0, 0, 0);
      }
    }
  }
  float inv[4];
#pragma unroll
  for (int r = 0; r < 4; ++r) inv[r] = 1.0f / lrow[r];
#pragma unroll
  for (int t = 0; t < 8; ++t) {
    int col = h * HD + t * 16 + l16;
#pragma unroll
    for (int r = 0; r < 4; ++r) {
      int row = q0 + wave * 16 + quad * 4 + r;
      O[(size_t)(b * SEQ + row) * (NH * HD) + col] = f2bf(oacc[t][r] * inv[r]);
    }
  }
}

extern "C" void kernel_launch(void* const* d_in, const int* in_sizes, int n_in,
                              void* d_out, int out_size, void* d_ws, size_t ws_size,
                              hipStream_t stream) {
  const float* hidden = (const float*)d_in[0];
  const float* cosb   = (const float*)d_in[1];
  const float* sinb   = (const float*)d_in[2];
  const float* Wq     = (const float*)d_in[3];
  const float* Wk     = (const float*)d_in[4];
  const float* Wv     = (const float*)d_in[5];
  const float* Wo     = (const float*)d_in[6];
  const float* qw     = (const float*)d_in[7];
  const float* kw     = (const float*)d_in[8];
  (void)in_sizes; (void)n_in; (void)out_size; (void)ws_size;

  char* ws = (char*)d_ws;
  size_t off = 0;
  auto alloc = [&](size_t n) { char* p = ws + off; off += (n + 255) & ~(size_t)255; return p; };

  unsigned short* hb  = (unsigned short*)alloc((size_t)MT * HIDDEN * 2);  // hidden bf16 (16 MB)
  unsigned short* wqt = (unsigned short*)alloc((size_t)2048 * 2048 * 2);  // Wq^T bf16 [N][K] (8 MB)
  unsigned short* wkt = (unsigned short*)alloc((size_t)512 * 2048 * 2);   // (2 MB)
  unsigned short* wvt = (unsigned short*)alloc((size_t)512 * 2048 * 2);   // (2 MB)
  unsigned short* wot = (unsigned short*)alloc((size_t)2048 * 2048 * 2);  // (8 MB)
  float* kraw = (float*)alloc((size_t)MT * 512 * 4);                      // (8 MB)
  float* vraw = (float*)alloc((size_t)MT * 512 * 4);                      // (8 MB)
  unsigned short* Qb  = (unsigned short*)alloc((size_t)MT * 2048 * 2);  // [NB][NH][SEQ][HD] (16 MB)
  unsigned short* Kbb = (unsigned short*)alloc((size_t)MT * 512 * 2);   // [NB][NKV][SEQ][HD] (4 MB)
  unsigned short* Vtb = (unsigned short*)alloc((size_t)MT * 512 * 2);   // [NB][NKV][HD][SEQ] (4 MB)
  unsigned short* Ob  = (unsigned short*)alloc((size_t)MT * 2048 * 2);  // attn out [MT][NH*HD] (16 MB)
  // d_out (32 MB fp32) doubles as Q-GEMM scratch; consumed by norm_rope(Q)
  // before the final GEMM overwrites it. Peak ws ~= 92 MB.
  float* qraw = (float*)d_out;

  cast_bf16_kernel<<<(MT * HIDDEN / 4) / 256, 256, 0, stream>>>(hidden, hb, MT * HIDDEN / 4);
  dim3 tb(32, 8);
  transpose_bf16_kernel<<<dim3(64, 64), tb, 0, stream>>>(Wq, wqt, 2048, 2048);
  transpose_bf16_kernel<<<dim3(16, 64), tb, 0, stream>>>(Wk, wkt, 2048, 512);
  transpose_bf16_kernel<<<dim3(16, 64), tb, 0, stream>>>(Wv, wvt, 2048, 512);
  transpose_bf16_kernel<<<dim3(64, 64), tb, 0, stream>>>(Wo, wot, 2048, 2048);

  gemm_bf16_kernel<<<dim3(MT / 128, 16), 256, 0, stream>>>(hb, wqt, qraw, MT, 2048, 2048);
  gemm_bf16_kernel<<<dim3(MT / 128, 4), 256, 0, stream>>>(hb, wkt, kraw, MT, 512, 2048);
  gemm_bf16_kernel<<<dim3(MT / 128, 4), 256, 0, stream>>>(hb, wvt, vraw, MT, 512, 2048);

  norm_rope_kernel<<<MT * NH / 4, 256, 0, stream>>>(qraw, qw, cosb, sinb, Qb, NH);
  norm_rope_kernel<<<MT * NKV / 4, 256, 0, stream>>>(kraw, kw, cosb, sinb, Kbb, NKV);
  v_cast_kernel<<<(NB * NKV * HD * SEQ) / 256, 256, 0, stream>>>(vraw, Vtb);

  attn_kernel<<<dim3(SEQ / 64, NB * NH), 256, 0, stream>>>(Qb, Kbb, Vtb, Ob);

  gemm_bf16_kernel<<<dim3(MT / 128, 16), 256, 0, stream>>>(Ob, wot, (float*)d_out, MT, 2048, 2048);
}

// Round 3
// 515.612 us; speedup vs baseline: 1.3218x; 1.3218x over previous
//
#include <hip/hip_runtime.h>

typedef float floatx4 __attribute__((ext_vector_type(4)));
typedef short short8 __attribute__((ext_vector_type(8)));

#define HIDDEN 2048
#define NH 16
#define NKV 4
#define HD 128
#define NB 2
#define SEQ 2048
#define MT (NB * SEQ)  // 4096

__device__ __forceinline__ unsigned short f2bf(float x) {
  union { float f; unsigned u; } v; v.f = x;
  unsigned r = v.u + 0x7FFFu + ((v.u >> 16) & 1u);  // RNE
  return (unsigned short)(r >> 16);
}

// ---------------- contiguous fp32 -> bf16 cast ----------------
__global__ void cast_bf16_kernel(const float* __restrict__ in,
                                 unsigned short* __restrict__ out, int n4) {
  int i = blockIdx.x * 256 + threadIdx.x;
  if (i >= n4) return;
  float4 v = ((const float4*)in)[i];
  ushort4 o;
  o.x = f2bf(v.x); o.y = f2bf(v.y); o.z = f2bf(v.z); o.w = f2bf(v.w);
  ((ushort4*)out)[i] = o;
}

// ------- transpose + cast: W[Kd][Nd] fp32 -> Wt[Nd][Kd] bf16 -------
__global__ void transpose_bf16_kernel(const float* __restrict__ W,
                                      unsigned short* __restrict__ Wt,
                                      int Kd, int Nd) {
  __shared__ float tile[32][33];
  int n0 = blockIdx.x * 32, k0 = blockIdx.y * 32;
  int tx = threadIdx.x, ty = threadIdx.y;
  for (int i = 0; i < 32; i += 8)
    tile[ty + i][tx] = W[(size_t)(k0 + ty + i) * Nd + n0 + tx];
  __syncthreads();
  for (int i = 0; i < 32; i += 8)
    Wt[(size_t)(n0 + ty + i) * Kd + k0 + tx] = f2bf(tile[tx][ty + i]);
}

// ------- C[M][N] fp32 = A[M][K] bf16 @ Bt[N][K]^T bf16 -------
// 128x128 tile, BK=32, 4 waves in 2x2, 16x16x32 MFMA.
#define LDK 40  // padded LDS k-stride (bf16 units): 80B rows -> 2-way bank alias (free)

__global__ __launch_bounds__(256, 2)
void gemm_bf16_kernel(const unsigned short* __restrict__ A,
                      const unsigned short* __restrict__ Bt,
                      float* __restrict__ C, int M, int N, int K) {
  __shared__ unsigned short As[128 * LDK];
  __shared__ unsigned short Bs[128 * LDK];
  const int tid = threadIdx.x;
  const int wave = tid >> 6, lane = tid & 63;
  const int quad = lane >> 4, l16 = lane & 15;
  const int m0 = blockIdx.x * 128, n0 = blockIdx.y * 128;
  const int wm = (wave >> 1) * 64, wn = (wave & 1) * 64;

  floatx4 acc[4][4] = {};

  for (int kt = 0; kt < K; kt += 32) {
    __syncthreads();
    for (int c = tid; c < 512; c += 256) {
      int r = c >> 2, c4 = c & 3;
      uint4 w = *(const uint4*)&A[(size_t)(m0 + r) * K + kt + c4 * 8];
      *(uint2*)&As[r * LDK + c4 * 8] = make_uint2(w.x, w.y);
      *(uint2*)&As[r * LDK + c4 * 8 + 4] = make_uint2(w.z, w.w);
      uint4 v = *(const uint4*)&Bt[(size_t)(n0 + r) * K + kt + c4 * 8];
      *(uint2*)&Bs[r * LDK + c4 * 8] = make_uint2(v.x, v.y);
      *(uint2*)&Bs[r * LDK + c4 * 8 + 4] = make_uint2(v.z, v.w);
    }
    __syncthreads();
    short8 af[4], bf[4];
#pragma unroll
    for (int i = 0; i < 4; i++)
      af[i] = *(const short8*)&As[(wm + i * 16 + l16) * LDK + quad * 8];
#pragma unroll
    for (int j = 0; j < 4; j++)
      bf[j] = *(const short8*)&Bs[(wn + j * 16 + l16) * LDK + quad * 8];
#pragma unroll
    for (int i = 0; i < 4; i++)
#pragma unroll
      for (int j = 0; j < 4; j++)
        acc[i][j] = __builtin_amdgcn_mfma_f32_16x16x32_bf16(af[i], bf[j], acc[i][j], 0, 0, 0);
  }
#pragma unroll
  for (int i = 0; i < 4; i++) {
    int row = m0 + wm + i * 16 + quad * 4;
#pragma unroll
    for (int j = 0; j < 4; j++) {
      int col = n0 + wn + j * 16 + l16;
#pragma unroll
      for (int r = 0; r < 4; r++)
        C[(size_t)(row + r) * N + col] = acc[i][j][r];
    }
  }
}

// ------- per-head RMSNorm + RoPE + cast, X[MT][Nh*HD] fp32 -> out[NB][Nh][SEQ][HD] bf16 -------
__global__ void norm_rope_kernel(const float* __restrict__ X,
                                 const float* __restrict__ w,
                                 const float* __restrict__ cosb,
                                 const float* __restrict__ sinb,
                                 unsigned short* __restrict__ out, int Nh) {
  int rid = blockIdx.x * 4 + (threadIdx.x >> 6);
  int lane = threadIdx.x & 63;
  int m = rid / Nh, h = rid - m * Nh;
  int b = m / SEQ, s = m - b * SEQ;
  const float* x = X + (size_t)m * (Nh * HD) + h * HD;
  float x0 = x[lane], x1 = x[lane + 64];
  float ssq = x0 * x0 + x1 * x1;
#pragma unroll
  for (int off = 32; off >= 1; off >>= 1) ssq += __shfl_xor(ssq, off, 64);
  float rr = rsqrtf(ssq * (1.0f / 128.0f) + 1e-6f);
  float xn0 = x0 * rr * w[lane];
  float xn1 = x1 * rr * w[lane + 64];
  float c0 = cosb[s * HD + lane], c1 = cosb[s * HD + lane + 64];
  float s0 = sinb[s * HD + lane], s1 = sinb[s * HD + lane + 64];
  unsigned short* op = out + (size_t)((b * Nh + h) * SEQ + s) * HD;
  op[lane] = f2bf(xn0 * c0 - xn1 * s0);       // d < 64:  x*c - x[d+64]*s
  op[lane + 64] = f2bf(xn1 * c1 + xn0 * s1);  // d >= 64: x*c + x[d-64]*s
}

// ------- V transpose + cast (tiled, coalesced): Vraw[MT][NKV*HD] fp32 -> Vt[NB][NKV][HD][SEQ] bf16 -------
__global__ void v_transpose_kernel(const float* __restrict__ Vraw,
                                   unsigned short* __restrict__ Vt) {
  __shared__ float tile[32][33];
  int d0 = blockIdx.x * 32;   // 4 blocks over HD
  int s0 = blockIdx.y * 32;   // 64 blocks over SEQ
  int bkv = blockIdx.z;       // 8: b*NKV+kv
  int b = bkv >> 2, kv = bkv & 3;
  int tx = threadIdx.x, ty = threadIdx.y;
  const float* src = Vraw + (size_t)(b * SEQ + s0) * (NKV * HD) + kv * HD + d0;
  for (int i = 0; i < 32; i += 8)
    tile[ty + i][tx] = src[(size_t)(ty + i) * (NKV * HD) + tx];  // coalesced over d
  __syncthreads();
  unsigned short* dst = Vt + (size_t)(bkv * HD + d0) * SEQ + s0;
  for (int i = 0; i < 32; i += 8)
    dst[(size_t)(ty + i) * SEQ + tx] = f2bf(tile[tx][ty + i]);   // coalesced over s
}

// ------- flash attention, GQA, causal -------
// block = 4 waves; 64 q-rows per block; kv tiles of 128; each wave owns 16 q-rows.
// LPT grid order: high-work q-tiles launch first.
#define LQ 136  // LDS stride for [*][128] bf16 tiles (272B rows, 16B-aligned, 2-way alias = free)

__global__ __launch_bounds__(256, 2)
void attn_kernel(const unsigned short* __restrict__ Q,   // [NB][NH][SEQ][HD]
                 const unsigned short* __restrict__ Kb,  // [NB][NKV][SEQ][HD]
                 const unsigned short* __restrict__ Vt,  // [NB][NKV][HD][SEQ]
                 unsigned short* __restrict__ O) {       // [MT][NH*HD]
  __shared__ unsigned short Qs[64 * LQ];    // 17408 B
  __shared__ unsigned short KVs[128 * LQ];  // 34816 B: K-tile [kv=128][d=128] / V-tile [d=128][kv=128]
  __shared__ unsigned short Ps[64 * LQ];    // 17408 B: P [q=64][kv=128]
  const int tid = threadIdx.x;
  const int wave = tid >> 6, lane = tid & 63;
  const int quad = lane >> 4, l16 = lane & 15;
  // LPT: qt descending with blockIdx.x so longest blocks dispatch first
  const int qt = (SEQ / 64 - 1) - (blockIdx.x >> 5);
  const int bh = blockIdx.x & 31;
  const int b = bh >> 4, h = bh & 15, kvh = h >> 2;
  const int q0 = qt * 64;
  const int nkt = (qt >> 1) + 1;  // number of 128-wide kv tiles

  // stage Q tile: 64 rows x 128 bf16 = 1024 x 16B
  const unsigned short* Qg = Q + (size_t)((b * NH + h) * SEQ + q0) * HD;
  for (int c = tid; c < 1024; c += 256) {
    int r = c >> 4, c8 = c & 15;
    *(uint4*)&Qs[r * LQ + c8 * 8] = *(const uint4*)&Qg[r * HD + c8 * 8];
  }

  floatx4 oacc[8] = {};
  float mrow[4] = {-1e30f, -1e30f, -1e30f, -1e30f};
  float lrow[4] = {0.f, 0.f, 0.f, 0.f};
  const float scale = 0.08838834764831845f;  // 1/sqrt(128)
  const unsigned short* Kg0 = Kb + (size_t)((b * NKV + kvh) * SEQ) * HD;
  const unsigned short* Vg0 = Vt + (size_t)((b * NKV + kvh) * HD) * SEQ;

  for (int kt = 0; kt < nkt; ++kt) {
    __syncthreads();  // prev PV reads done (and Q staged, first iter)
    // stage K tile: 128 rows x 128 bf16 = 2048 x 16B
    for (int c = tid; c < 2048; c += 256) {
      int r = c >> 4, c8 = c & 15;
      *(uint4*)&KVs[r * LQ + c8 * 8] = *(const uint4*)&Kg0[(size_t)(kt * 128 + r) * HD + c8 * 8];
    }
    __syncthreads();
    // S = Q @ K^T : wave rows wave*16.., cols 0..127
    floatx4 sc[8] = {};
#pragma unroll
    for (int ks = 0; ks < 4; ++ks) {
      short8 af = *(const short8*)&Qs[(wave * 16 + l16) * LQ + ks * 32 + quad * 8];
#pragma unroll
      for (int j = 0; j < 8; ++j) {
        short8 bf = *(const short8*)&KVs[(j * 16 + l16) * LQ + ks * 32 + quad * 8];
        sc[j] = __builtin_amdgcn_mfma_f32_16x16x32_bf16(af, bf, sc[j], 0, 0, 0);
      }
    }
#pragma unroll
    for (int j = 0; j < 8; ++j)
#pragma unroll
      for (int r = 0; r < 4; ++r) sc[j][r] *= scale;
    if (kt == nkt - 1) {  // only the last tile can contain masked columns
      int rowg = q0 + wave * 16 + quad * 4;
#pragma unroll
      for (int j = 0; j < 8; ++j) {
        int col = kt * 128 + j * 16 + l16;
#pragma unroll
        for (int r = 0; r < 4; ++r)
          if (col > rowg + r) sc[j][r] = -1e30f;
      }
    }
    // online softmax; row r lives in this 16-lane group
    float alpha[4];
#pragma unroll
    for (int r = 0; r < 4; ++r) {
      float mx = sc[0][r];
#pragma unroll
      for (int j = 1; j < 8; ++j) mx = fmaxf(mx, sc[j][r]);
#pragma unroll
      for (int off = 1; off < 16; off <<= 1) mx = fmaxf(mx, __shfl_xor(mx, off, 64));
      float mn = fmaxf(mrow[r], mx);
      alpha[r] = __expf(mrow[r] - mn);
      mrow[r] = mn;
      float rs = 0.f;
#pragma unroll
      for (int j = 0; j < 8; ++j) {
        float p = __expf(sc[j][r] - mn);
        sc[j][r] = p;
        rs += p;
      }
#pragma unroll
      for (int off = 1; off < 16; off <<= 1) rs += __shfl_xor(rs, off, 64);
      lrow[r] = lrow[r] * alpha[r] + rs;
    }
#pragma unroll
    for (int t = 0; t < 8; ++t)
#pragma unroll
      for (int r = 0; r < 4; ++r) oacc[t][r] *= alpha[r];
    // P (C-layout) -> LDS -> A-layout for PV
#pragma unroll
    for (int j = 0; j < 8; ++j)
#pragma unroll
      for (int r = 0; r < 4; ++r)
        Ps[(wave * 16 + quad * 4 + r) * LQ + j * 16 + l16] = f2bf(sc[j][r]);
    __syncthreads();  // all waves' K reads done before V overwrites KVs
    // stage V tile as [d=128][kv=128] = 2048 x 16B
    for (int c = tid; c < 2048; c += 256) {
      int d = c >> 4, c8 = c & 15;
      *(uint4*)&KVs[d * LQ + c8 * 8] = *(const uint4*)&Vg0[(size_t)d * SEQ + kt * 128 + c8 * 8];
    }
    __syncthreads();
    // O += P @ V  (kv is the K-dim, 128 = 4 x 32)
#pragma unroll
    for (int ks = 0; ks < 4; ++ks) {
      short8 af = *(const short8*)&Ps[(wave * 16 + l16) * LQ + ks * 32 + quad * 8];
#pragma unroll
      for (int t = 0; t < 8; ++t) {
        short8 bf = *(const short8*)&KVs[(t * 16 + l16) * LQ + ks * 32 + quad * 8];
        oacc[t] = __builtin_amdgcn_mfma_f32_16x16x32_bf16(af, bf, oacc[t], 0, 0, 0);
      }
    }
  }
  float inv[4];
#pragma unroll
  for (int r = 0; r < 4; ++r) inv[r] = 1.0f / lrow[r];
#pragma unroll
  for (int t = 0; t < 8; ++t) {
    int col = h * HD + t * 16 + l16;
#pragma unroll
    for (int r = 0; r < 4; ++r) {
      int row = q0 + wave * 16 + quad * 4 + r;
      O[(size_t)(b * SEQ + row) * (NH * HD) + col] = f2bf(oacc[t][r] * inv[r]);
    }
  }
}

extern "C" void kernel_launch(void* const* d_in, const int* in_sizes, int n_in,
                              void* d_out, int out_size, void* d_ws, size_t ws_size,
                              hipStream_t stream) {
  const float* hidden = (const float*)d_in[0];
  const float* cosb   = (const float*)d_in[1];
  const float* sinb   = (const float*)d_in[2];
  const float* Wq     = (const float*)d_in[3];
  const float* Wk     = (const float*)d_in[4];
  const float* Wv     = (const float*)d_in[5];
  const float* Wo     = (const float*)d_in[6];
  const float* qw     = (const float*)d_in[7];
  const float* kw     = (const float*)d_in[8];
  (void)in_sizes; (void)n_in; (void)out_size; (void)ws_size;

  char* ws = (char*)d_ws;
  size_t off = 0;
  auto alloc = [&](size_t n) { char* p = ws + off; off += (n + 255) & ~(size_t)255; return p; };

  unsigned short* hb  = (unsigned short*)alloc((size_t)MT * HIDDEN * 2);  // hidden bf16 (16 MB)
  unsigned short* wqt = (unsigned short*)alloc((size_t)2048 * 2048 * 2);  // Wq^T bf16 [N][K] (8 MB)
  unsigned short* wkt = (unsigned short*)alloc((size_t)512 * 2048 * 2);   // (2 MB)
  unsigned short* wvt = (unsigned short*)alloc((size_t)512 * 2048 * 2);   // (2 MB)
  unsigned short* wot = (unsigned short*)alloc((size_t)2048 * 2048 * 2);  // (8 MB)
  float* kraw = (float*)alloc((size_t)MT * 512 * 4);                      // (8 MB)
  float* vraw = (float*)alloc((size_t)MT * 512 * 4);                      // (8 MB)
  unsigned short* Qb  = (unsigned short*)alloc((size_t)MT * 2048 * 2);  // [NB][NH][SEQ][HD] (16 MB)
  unsigned short* Kbb = (unsigned short*)alloc((size_t)MT * 512 * 2);   // [NB][NKV][SEQ][HD] (4 MB)
  unsigned short* Vtb = (unsigned short*)alloc((size_t)MT * 512 * 2);   // [NB][NKV][HD][SEQ] (4 MB)
  unsigned short* Ob  = (unsigned short*)alloc((size_t)MT * 2048 * 2);  // attn out [MT][NH*HD] (16 MB)
  // d_out (32 MB fp32) doubles as Q-GEMM scratch; consumed by norm_rope(Q)
  // before the final GEMM overwrites it. Peak ws ~= 92 MB.
  float* qraw = (float*)d_out;

  cast_bf16_kernel<<<(MT * HIDDEN / 4) / 256, 256, 0, stream>>>(hidden, hb, MT * HIDDEN / 4);
  dim3 tb(32, 8);
  transpose_bf16_kernel<<<dim3(64, 64), tb, 0, stream>>>(Wq, wqt, 2048, 2048);
  transpose_bf16_kernel<<<dim3(16, 64), tb, 0, stream>>>(Wk, wkt, 2048, 512);
  transpose_bf16_kernel<<<dim3(16, 64), tb, 0, stream>>>(Wv, wvt, 2048, 512);
  transpose_bf16_kernel<<<dim3(64, 64), tb, 0, stream>>>(Wo, wot, 2048, 2048);

  gemm_bf16_kernel<<<dim3(MT / 128, 16), 256, 0, stream>>>(hb, wqt, qraw, MT, 2048, 2048);
  gemm_bf16_kernel<<<dim3(MT / 128, 4), 256, 0, stream>>>(hb, wkt, kraw, MT, 512, 2048);
  gemm_bf16_kernel<<<dim3(MT / 128, 4), 256, 0, stream>>>(hb, wvt, vraw, MT, 512, 2048);

  norm_rope_kernel<<<MT * NH / 4, 256, 0, stream>>>(qraw, qw, cosb, sinb, Qb, NH);
  norm_rope_kernel<<<MT * NKV / 4, 256, 0, stream>>>(kraw, kw, cosb, sinb, Kbb, NKV);
  v_transpose_kernel<<<dim3(HD / 32, SEQ / 32, NB * NKV), tb, 0, stream>>>(vraw, Vtb);

  attn_kernel<<<(SEQ / 64) * 32, 256, 0, stream>>>(Qb, Kbb, Vtb, Ob);

  gemm_bf16_kernel<<<dim3(MT / 128, 16), 256, 0, stream>>>(Ob, wot, (float*)d_out, MT, 2048, 2048);
}

// Round 4
// 431.854 us; speedup vs baseline: 1.5781x; 1.1940x over previous
//
#include <hip/hip_runtime.h>

typedef float floatx4 __attribute__((ext_vector_type(4)));
typedef short short8 __attribute__((ext_vector_type(8)));

#define HIDDEN 2048
#define NH 16
#define NKV 4
#define HD 128
#define NB 2
#define SEQ 2048
#define MT (NB * SEQ)  // 4096

__device__ __forceinline__ unsigned short f2bf(float x) {
  union { float f; unsigned u; } v; v.f = x;
  unsigned r = v.u + 0x7FFFu + ((v.u >> 16) & 1u);  // RNE
  return (unsigned short)(r >> 16);
}

// ---------------- contiguous fp32 -> bf16 cast ----------------
__global__ void cast_bf16_kernel(const float* __restrict__ in,
                                 unsigned short* __restrict__ out, int n4) {
  int i = blockIdx.x * 256 + threadIdx.x;
  if (i >= n4) return;
  float4 v = ((const float4*)in)[i];
  ushort4 o;
  o.x = f2bf(v.x); o.y = f2bf(v.y); o.z = f2bf(v.z); o.w = f2bf(v.w);
  ((ushort4*)out)[i] = o;
}

// ------- transpose + cast: W[Kd][Nd] fp32 -> Wt[Nd][Kd] bf16 -------
__global__ void transpose_bf16_kernel(const float* __restrict__ W,
                                      unsigned short* __restrict__ Wt,
                                      int Kd, int Nd) {
  __shared__ float tile[32][33];
  int n0 = blockIdx.x * 32, k0 = blockIdx.y * 32;
  int tx = threadIdx.x, ty = threadIdx.y;
  for (int i = 0; i < 32; i += 8)
    tile[ty + i][tx] = W[(size_t)(k0 + ty + i) * Nd + n0 + tx];
  __syncthreads();
  for (int i = 0; i < 32; i += 8)
    Wt[(size_t)(n0 + ty + i) * Kd + k0 + tx] = f2bf(tile[tx][ty + i]);
}

// ------- C[M][N] fp32 = A[M][K] bf16 @ Bt[N][K]^T bf16 -------
// m97 structure: 128x128 tile, BK=32, 4 waves 2x2, 16x16x32 MFMA,
// global_load_lds width-16 staging into UNPADDED [128][32] LDS tiles
// (global_load_lds requires dst = wave-uniform base + lane*16; no padding).
__global__ __launch_bounds__(256, 3)
void gemm_bf16_kernel(const unsigned short* __restrict__ A,
                      const unsigned short* __restrict__ Bt,
                      float* __restrict__ C, int M, int N, int K) {
  __shared__ unsigned short As[128 * 32];
  __shared__ unsigned short Bs[128 * 32];
  const int tid = threadIdx.x;
  const int wave = tid >> 6, lane = tid & 63;
  const int quad = lane >> 4, l16 = lane & 15;
  const int m0 = blockIdx.x * 128, n0 = blockIdx.y * 128;
  const int wm = (wave >> 1) * 64, wn = (wave & 1) * 64;
  // staging: chunk q = wave*2+t covers rows q*16..q*16+15; lane -> row q*16+lane/4, col (lane&3)*8
  const int srow = lane >> 2;
  const int scol = (lane & 3) * 8;

  floatx4 acc[4][4] = {};

  for (int kt = 0; kt < K; kt += 32) {
    __syncthreads();
#pragma unroll
    for (int t = 0; t < 2; ++t) {
      int q = wave * 2 + t;
      int row = q * 16 + srow;
      __builtin_amdgcn_global_load_lds(
          (const __attribute__((address_space(1))) unsigned int*)&A[(size_t)(m0 + row) * K + kt + scol],
          (__attribute__((address_space(3))) unsigned int*)&As[q * 16 * 32],
          16, 0, 0);
      __builtin_amdgcn_global_load_lds(
          (const __attribute__((address_space(1))) unsigned int*)&Bt[(size_t)(n0 + row) * K + kt + scol],
          (__attribute__((address_space(3))) unsigned int*)&Bs[q * 16 * 32],
          16, 0, 0);
    }
    __syncthreads();
    short8 af[4], bf[4];
#pragma unroll
    for (int i = 0; i < 4; i++)
      af[i] = *(const short8*)&As[(wm + i * 16 + l16) * 32 + quad * 8];
#pragma unroll
    for (int j = 0; j < 4; j++)
      bf[j] = *(const short8*)&Bs[(wn + j * 16 + l16) * 32 + quad * 8];
#pragma unroll
    for (int i = 0; i < 4; i++)
#pragma unroll
      for (int j = 0; j < 4; j++)
        acc[i][j] = __builtin_amdgcn_mfma_f32_16x16x32_bf16(af[i], bf[j], acc[i][j], 0, 0, 0);
  }
#pragma unroll
  for (int i = 0; i < 4; i++) {
    int row = m0 + wm + i * 16 + quad * 4;
#pragma unroll
    for (int j = 0; j < 4; j++) {
      int col = n0 + wn + j * 16 + l16;
#pragma unroll
      for (int r = 0; r < 4; r++)
        C[(size_t)(row + r) * N + col] = acc[i][j][r];
    }
  }
}

// ------- per-head RMSNorm + RoPE + cast, X[MT][Nh*HD] fp32 -> out[NB][Nh][SEQ][HD] bf16 -------
__global__ void norm_rope_kernel(const float* __restrict__ X,
                                 const float* __restrict__ w,
                                 const float* __restrict__ cosb,
                                 const float* __restrict__ sinb,
                                 unsigned short* __restrict__ out, int Nh) {
  int rid = blockIdx.x * 4 + (threadIdx.x >> 6);
  int lane = threadIdx.x & 63;
  int m = rid / Nh, h = rid - m * Nh;
  int b = m / SEQ, s = m - b * SEQ;
  const float* x = X + (size_t)m * (Nh * HD) + h * HD;
  float x0 = x[lane], x1 = x[lane + 64];
  float ssq = x0 * x0 + x1 * x1;
#pragma unroll
  for (int off = 32; off >= 1; off >>= 1) ssq += __shfl_xor(ssq, off, 64);
  float rr = rsqrtf(ssq * (1.0f / 128.0f) + 1e-6f);
  float xn0 = x0 * rr * w[lane];
  float xn1 = x1 * rr * w[lane + 64];
  float c0 = cosb[s * HD + lane], c1 = cosb[s * HD + lane + 64];
  float s0 = sinb[s * HD + lane], s1 = sinb[s * HD + lane + 64];
  unsigned short* op = out + (size_t)((b * Nh + h) * SEQ + s) * HD;
  op[lane] = f2bf(xn0 * c0 - xn1 * s0);       // d < 64:  x*c - x[d+64]*s
  op[lane + 64] = f2bf(xn1 * c1 + xn0 * s1);  // d >= 64: x*c + x[d-64]*s
}

// ------- V transpose + cast (tiled, coalesced): Vraw[MT][NKV*HD] fp32 -> Vt[NB][NKV][HD][SEQ] bf16 -------
__global__ void v_transpose_kernel(const float* __restrict__ Vraw,
                                   unsigned short* __restrict__ Vt) {
  __shared__ float tile[32][33];
  int d0 = blockIdx.x * 32;   // 4 blocks over HD
  int s0 = blockIdx.y * 32;   // 64 blocks over SEQ
  int bkv = blockIdx.z;       // 8: b*NKV+kv
  int b = bkv >> 2, kv = bkv & 3;
  int tx = threadIdx.x, ty = threadIdx.y;
  const float* src = Vraw + (size_t)(b * SEQ + s0) * (NKV * HD) + kv * HD + d0;
  for (int i = 0; i < 32; i += 8)
    tile[ty + i][tx] = src[(size_t)(ty + i) * (NKV * HD) + tx];  // coalesced over d
  __syncthreads();
  unsigned short* dst = Vt + (size_t)(bkv * HD + d0) * SEQ + s0;
  for (int i = 0; i < 32; i += 8)
    dst[(size_t)(ty + i) * SEQ + tx] = f2bf(tile[tx][ty + i]);   // coalesced over s
}

// ------- flash attention, GQA, causal -------
// block = 4 waves; 64 q-rows per block; kv tiles of 128; each wave owns 16 q-rows.
// LPT grid order: high-work q-tiles launch first.
#define LQ 136  // LDS stride for [*][128] bf16 tiles (272B rows, 16B-aligned, 2-way alias = free)

__global__ __launch_bounds__(256, 2)
void attn_kernel(const unsigned short* __restrict__ Q,   // [NB][NH][SEQ][HD]
                 const unsigned short* __restrict__ Kb,  // [NB][NKV][SEQ][HD]
                 const unsigned short* __restrict__ Vt,  // [NB][NKV][HD][SEQ]
                 unsigned short* __restrict__ O) {       // [MT][NH*HD]
  __shared__ unsigned short Qs[64 * LQ];    // 17408 B
  __shared__ unsigned short KVs[128 * LQ];  // 34816 B: K-tile [kv=128][d=128] / V-tile [d=128][kv=128]
  __shared__ unsigned short Ps[64 * LQ];    // 17408 B: P [q=64][kv=128]
  const int tid = threadIdx.x;
  const int wave = tid >> 6, lane = tid & 63;
  const int quad = lane >> 4, l16 = lane & 15;
  // LPT: qt descending with blockIdx.x so longest blocks dispatch first
  const int qt = (SEQ / 64 - 1) - (blockIdx.x >> 5);
  const int bh = blockIdx.x & 31;
  const int b = bh >> 4, h = bh & 15, kvh = h >> 2;
  const int q0 = qt * 64;
  const int nkt = (qt >> 1) + 1;  // number of 128-wide kv tiles

  // stage Q tile: 64 rows x 128 bf16 = 1024 x 16B
  const unsigned short* Qg = Q + (size_t)((b * NH + h) * SEQ + q0) * HD;
  for (int c = tid; c < 1024; c += 256) {
    int r = c >> 4, c8 = c & 15;
    *(uint4*)&Qs[r * LQ + c8 * 8] = *(const uint4*)&Qg[r * HD + c8 * 8];
  }

  floatx4 oacc[8] = {};
  float mrow[4] = {-1e30f, -1e30f, -1e30f, -1e30f};
  float lrow[4] = {0.f, 0.f, 0.f, 0.f};
  const float scale = 0.08838834764831845f;  // 1/sqrt(128)
  const unsigned short* Kg0 = Kb + (size_t)((b * NKV + kvh) * SEQ) * HD;
  const unsigned short* Vg0 = Vt + (size_t)((b * NKV + kvh) * HD) * SEQ;

  for (int kt = 0; kt < nkt; ++kt) {
    __syncthreads();  // prev PV reads done (and Q staged, first iter)
    // stage K tile: 128 rows x 128 bf16 = 2048 x 16B
    for (int c = tid; c < 2048; c += 256) {
      int r = c >> 4, c8 = c & 15;
      *(uint4*)&KVs[r * LQ + c8 * 8] = *(const uint4*)&Kg0[(size_t)(kt * 128 + r) * HD + c8 * 8];
    }
    __syncthreads();
    // S = Q @ K^T : wave rows wave*16.., cols 0..127
    floatx4 sc[8] = {};
#pragma unroll
    for (int ks = 0; ks < 4; ++ks) {
      short8 af = *(const short8*)&Qs[(wave * 16 + l16) * LQ + ks * 32 + quad * 8];
#pragma unroll
      for (int j = 0; j < 8; ++j) {
        short8 bf = *(const short8*)&KVs[(j * 16 + l16) * LQ + ks * 32 + quad * 8];
        sc[j] = __builtin_amdgcn_mfma_f32_16x16x32_bf16(af, bf, sc[j], 0, 0, 0);
      }
    }
#pragma unroll
    for (int j = 0; j < 8; ++j)
#pragma unroll
      for (int r = 0; r < 4; ++r) sc[j][r] *= scale;
    if (kt == nkt - 1) {  // only the last tile can contain masked columns
      int rowg = q0 + wave * 16 + quad * 4;
#pragma unroll
      for (int j = 0; j < 8; ++j) {
        int col = kt * 128 + j * 16 + l16;
#pragma unroll
        for (int r = 0; r < 4; ++r)
          if (col > rowg + r) sc[j][r] = -1e30f;
      }
    }
    // online softmax; row r lives in this 16-lane group
    float alpha[4];
#pragma unroll
    for (int r = 0; r < 4; ++r) {
      float mx = sc[0][r];
#pragma unroll
      for (int j = 1; j < 8; ++j) mx = fmaxf(mx, sc[j][r]);
#pragma unroll
      for (int off = 1; off < 16; off <<= 1) mx = fmaxf(mx, __shfl_xor(mx, off, 64));
      float mn = fmaxf(mrow[r], mx);
      alpha[r] = __expf(mrow[r] - mn);
      mrow[r] = mn;
      float rs = 0.f;
#pragma unroll
      for (int j = 0; j < 8; ++j) {
        float p = __expf(sc[j][r] - mn);
        sc[j][r] = p;
        rs += p;
      }
#pragma unroll
      for (int off = 1; off < 16; off <<= 1) rs += __shfl_xor(rs, off, 64);
      lrow[r] = lrow[r] * alpha[r] + rs;
    }
#pragma unroll
    for (int t = 0; t < 8; ++t)
#pragma unroll
      for (int r = 0; r < 4; ++r) oacc[t][r] *= alpha[r];
    // P (C-layout) -> LDS -> A-layout for PV
#pragma unroll
    for (int j = 0; j < 8; ++j)
#pragma unroll
      for (int r = 0; r < 4; ++r)
        Ps[(wave * 16 + quad * 4 + r) * LQ + j * 16 + l16] = f2bf(sc[j][r]);
    __syncthreads();  // all waves' K reads done before V overwrites KVs
    // stage V tile as [d=128][kv=128] = 2048 x 16B
    for (int c = tid; c < 2048; c += 256) {
      int d = c >> 4, c8 = c & 15;
      *(uint4*)&KVs[d * LQ + c8 * 8] = *(const uint4*)&Vg0[(size_t)d * SEQ + kt * 128 + c8 * 8];
    }
    __syncthreads();
    // O += P @ V  (kv is the K-dim, 128 = 4 x 32)
#pragma unroll
    for (int ks = 0; ks < 4; ++ks) {
      short8 af = *(const short8*)&Ps[(wave * 16 + l16) * LQ + ks * 32 + quad * 8];
#pragma unroll
      for (int t = 0; t < 8; ++t) {
        short8 bf = *(const short8*)&KVs[(t * 16 + l16) * LQ + ks * 32 + quad * 8];
        oacc[t] = __builtin_amdgcn_mfma_f32_16x16x32_bf16(af, bf, oacc[t], 0, 0, 0);
      }
    }
  }
  float inv[4];
#pragma unroll
  for (int r = 0; r < 4; ++r) inv[r] = 1.0f / lrow[r];
#pragma unroll
  for (int t = 0; t < 8; ++t) {
    int col = h * HD + t * 16 + l16;
#pragma unroll
    for (int r = 0; r < 4; ++r) {
      int row = q0 + wave * 16 + quad * 4 + r;
      O[(size_t)(b * SEQ + row) * (NH * HD) + col] = f2bf(oacc[t][r] * inv[r]);
    }
  }
}

extern "C" void kernel_launch(void* const* d_in, const int* in_sizes, int n_in,
                              void* d_out, int out_size, void* d_ws, size_t ws_size,
                              hipStream_t stream) {
  const float* hidden = (const float*)d_in[0];
  const float* cosb   = (const float*)d_in[1];
  const float* sinb   = (const float*)d_in[2];
  const float* Wq     = (const float*)d_in[3];
  const float* Wk     = (const float*)d_in[4];
  const float* Wv     = (const float*)d_in[5];
  const float* Wo     = (const float*)d_in[6];
  const float* qw     = (const float*)d_in[7];
  const float* kw     = (const float*)d_in[8];
  (void)in_sizes; (void)n_in; (void)out_size; (void)ws_size;

  char* ws = (char*)d_ws;
  size_t off = 0;
  auto alloc = [&](size_t n) { char* p = ws + off; off += (n + 255) & ~(size_t)255; return p; };

  unsigned short* hb  = (unsigned short*)alloc((size_t)MT * HIDDEN * 2);  // hidden bf16 (16 MB)
  unsigned short* wqt = (unsigned short*)alloc((size_t)2048 * 2048 * 2);  // Wq^T bf16 [N][K] (8 MB)
  unsigned short* wkt = (unsigned short*)alloc((size_t)512 * 2048 * 2);   // (2 MB)
  unsigned short* wvt = (unsigned short*)alloc((size_t)512 * 2048 * 2);   // (2 MB)
  unsigned short* wot = (unsigned short*)alloc((size_t)2048 * 2048 * 2);  // (8 MB)
  float* kraw = (float*)alloc((size_t)MT * 512 * 4);                      // (8 MB)
  float* vraw = (float*)alloc((size_t)MT * 512 * 4);                      // (8 MB)
  unsigned short* Qb  = (unsigned short*)alloc((size_t)MT * 2048 * 2);  // [NB][NH][SEQ][HD] (16 MB)
  unsigned short* Kbb = (unsigned short*)alloc((size_t)MT * 512 * 2);   // [NB][NKV][SEQ][HD] (4 MB)
  unsigned short* Vtb = (unsigned short*)alloc((size_t)MT * 512 * 2);   // [NB][NKV][HD][SEQ] (4 MB)
  unsigned short* Ob  = (unsigned short*)alloc((size_t)MT * 2048 * 2);  // attn out [MT][NH*HD] (16 MB)
  // d_out (32 MB fp32) doubles as Q-GEMM scratch; consumed by norm_rope(Q)
  // before the final GEMM overwrites it. Peak ws ~= 92 MB.
  float* qraw = (float*)d_out;

  cast_bf16_kernel<<<(MT * HIDDEN / 4) / 256, 256, 0, stream>>>(hidden, hb, MT * HIDDEN / 4);
  dim3 tb(32, 8);
  transpose_bf16_kernel<<<dim3(64, 64), tb, 0, stream>>>(Wq, wqt, 2048, 2048);
  transpose_bf16_kernel<<<dim3(16, 64), tb, 0, stream>>>(Wk, wkt, 2048, 512);
  transpose_bf16_kernel<<<dim3(16, 64), tb, 0, stream>>>(Wv, wvt, 2048, 512);
  transpose_bf16_kernel<<<dim3(64, 64), tb, 0, stream>>>(Wo, wot, 2048, 2048);

  gemm_bf16_kernel<<<dim3(MT / 128, 16), 256, 0, stream>>>(hb, wqt, qraw, MT, 2048, 2048);
  gemm_bf16_kernel<<<dim3(MT / 128, 4), 256, 0, stream>>>(hb, wkt, kraw, MT, 512, 2048);
  gemm_bf16_kernel<<<dim3(MT / 128, 4), 256, 0, stream>>>(hb, wvt, vraw, MT, 512, 2048);

  norm_rope_kernel<<<MT * NH / 4, 256, 0, stream>>>(qraw, qw, cosb, sinb, Qb, NH);
  norm_rope_kernel<<<MT * NKV / 4, 256, 0, stream>>>(kraw, kw, cosb, sinb, Kbb, NKV);
  v_transpose_kernel<<<dim3(HD / 32, SEQ / 32, NB * NKV), tb, 0, stream>>>(vraw, Vtb);

  attn_kernel<<<(SEQ / 64) * 32, 256, 0, stream>>>(Qb, Kbb, Vtb, Ob);

  gemm_bf16_kernel<<<dim3(MT / 128, 16), 256, 0, stream>>>(Ob, wot, (float*)d_out, MT, 2048, 2048);
}